// Round 4
// baseline (183.111 us; speedup 1.0000x reference)
//
#include <hip/hip_runtime.h>
#include <stdint.h>

// SingleHeadAttention: X(4,4096,768) f32; Wq/Wk/Wv(768,64); bq/bk/bv(64)
// out(4,4096,64) f32.
// wpack -> proj (barrier-free direct-load MFMA) -> attn (4-wave blocks,
// LDS K/V, split-K 512-key chunks, f16 partials) -> combine.

#define QSCALE 0.18033688011112042f  // log2(e)/sqrt(64): fold scale+base2 into Q

using short4v = __attribute__((ext_vector_type(4))) short;
using short8v = __attribute__((ext_vector_type(8))) short;
using float4v = __attribute__((ext_vector_type(4))) float;
using uint4v  = __attribute__((ext_vector_type(4))) unsigned int;
typedef unsigned long long ull;
typedef unsigned short ushort;

#if __has_builtin(__builtin_amdgcn_exp2f)
#define EXP2F(x) __builtin_amdgcn_exp2f(x)
#else
#define EXP2F(x) exp2f(x)
#endif

__device__ __forceinline__ ushort f2b(float f) {
  union { float f; unsigned u; } cv; cv.f = f;
  unsigned u = cv.u;
  u += 0x7FFFu + ((u >> 16) & 1u);   // RNE
  return (ushort)(u >> 16);
}
__device__ __forceinline__ ushort f2h(float f) {
  union { ushort u; _Float16 h; } cv; cv.h = (_Float16)f;
  return cv.u;
}
__device__ __forceinline__ float h2f(unsigned u16) {
  union { ushort u; _Float16 h; } cv; cv.u = (ushort)u16;
  return (float)cv.h;
}

// ---- P0: pack W transposed [n=192][e=768] bf16 via LDS bounce; biases f32 ----
__global__ void wpack_kernel(const float* __restrict__ Wq, const float* __restrict__ bq,
                             const float* __restrict__ Wk, const float* __restrict__ bk,
                             const float* __restrict__ Wv, const float* __restrict__ bv,
                             ushort* __restrict__ Wt, float* __restrict__ bb) {
  __shared__ float tile[64 * 65];
  const int t = threadIdx.x;
  const int m = blockIdx.x % 3, e0 = (blockIdx.x / 3) * 64;
  const float* Wsrc = (m == 0) ? Wq : (m == 1) ? Wk : Wv;
  const float sc = (m == 0) ? QSCALE : 1.0f;
#pragma unroll
  for (int i = 0; i < 16; ++i) {
    int idx = i * 256 + t, n = idx & 63, el = idx >> 6;
    tile[el * 65 + n] = Wsrc[(size_t)(e0 + el) * 64 + n];
  }
  __syncthreads();
#pragma unroll
  for (int i = 0; i < 16; ++i) {
    int idx = i * 256 + t, el = idx & 63, n = idx >> 6;
    Wt[(size_t)(m * 64 + n) * 768 + e0 + el] = f2b(tile[el * 65 + n] * sc);
  }
  if (blockIdx.x == 0 && t < 192) {
    float bvv;
    if (t < 64)       bvv = bq[t] * QSCALE;
    else if (t < 128) bvv = bk[t - 64];
    else              bvv = bv[t - 128];
    bb[t] = bvv;
  }
}

// ---- P1: QKV projection. 512 blocks x 32 rows, NO LDS/barriers: each wave
//          loads X f32 fragments direct from global, converts in-reg. ----
__global__ __launch_bounds__(256, 4) void proj_kernel(
    const float* __restrict__ X, const ushort* __restrict__ Wt,
    const float* __restrict__ bb,
    ushort* __restrict__ Qb, ushort* __restrict__ Kb, ushort* __restrict__ Vt) {
  const int t = threadIdx.x;
  const int wv = t >> 6, lane = t & 63, g = lane >> 4, r = lane & 15;
  const int row0 = blockIdx.x * 32;

  float4v acc[3][2];
#pragma unroll
  for (int ct = 0; ct < 3; ++ct) {
    float bias = bb[wv * 48 + ct * 16 + r];
#pragma unroll
    for (int rt = 0; rt < 2; ++rt) acc[ct][rt] = {bias, bias, bias, bias};
  }

  const float* xb = X + (size_t)(row0 + r) * 768 + g * 8;
  const ushort* wb = Wt + (size_t)(wv * 48 + r) * 768 + g * 8;

#pragma unroll 2
  for (int kc = 0; kc < 12; ++kc) {
    const int k0 = kc * 64;
    short8v af[2][2];
#pragma unroll
    for (int rt = 0; rt < 2; ++rt)
#pragma unroll
      for (int ks = 0; ks < 2; ++ks) {
        const float* xp = xb + rt * 16 * 768 + k0 + ks * 32;
        float4v x0 = *(const float4v*)xp;
        float4v x1 = *(const float4v*)(xp + 4);
        short8v v;
        v[0] = (short)f2b(x0[0]); v[1] = (short)f2b(x0[1]);
        v[2] = (short)f2b(x0[2]); v[3] = (short)f2b(x0[3]);
        v[4] = (short)f2b(x1[0]); v[5] = (short)f2b(x1[1]);
        v[6] = (short)f2b(x1[2]); v[7] = (short)f2b(x1[3]);
        af[rt][ks] = v;
      }
#pragma unroll
    for (int ct = 0; ct < 3; ++ct) {
      short8v b0 = *(const short8v*)(wb + ct * 16 * 768 + k0);
      short8v b1 = *(const short8v*)(wb + ct * 16 * 768 + k0 + 32);
#pragma unroll
      for (int rt = 0; rt < 2; ++rt) {
        acc[ct][rt] = __builtin_amdgcn_mfma_f32_16x16x32_bf16(af[rt][0], b0, acc[ct][rt], 0, 0, 0);
        acc[ct][rt] = __builtin_amdgcn_mfma_f32_16x16x32_bf16(af[rt][1], b1, acc[ct][rt], 0, 0, 0);
      }
    }
  }
#pragma unroll
  for (int ct = 0; ct < 3; ++ct) {
    int n = wv * 48 + ct * 16 + r;
    int mtx = n >> 6, dl = n & 63;
#pragma unroll
    for (int rt = 0; rt < 2; ++rt) {
#pragma unroll
      for (int i = 0; i < 4; ++i) {
        int rg = row0 + rt * 16 + g * 4 + i;
        ushort hv = f2b(acc[ct][rt][i]);
        if (mtx == 0)      Qb[rg * 64 + dl] = hv;
        else if (mtx == 1) Kb[rg * 64 + dl] = hv;
        else               Vt[(size_t)(((rg >> 12) << 6) + dl) * 4096 + (rg & 4095)] = hv;
      }
    }
  }
}

// ---- P2: flash attn. 4-wave blocks (64 q-rows), LDS K/V 64-key macro-tiles,
//          double-buffered; split-K chunks of 512 keys. 1152 blocks. ----
__global__ __launch_bounds__(256) void attn_kernel(
    const ushort* __restrict__ Qb, const ushort* __restrict__ Kb,
    const ushort* __restrict__ Vt, ushort* __restrict__ pacc,
    float* __restrict__ pml) {
  __shared__ char lds[32768];
  char* lk = lds;            // [2][64 key][128B], ^((key&7)<<4)
  char* lv = lds + 16384;    // [2][4 ks][64 d][4 slots*8B], slot^((d>>2)&3)^ks
  const int t = threadIdx.x;
  const int wv = t >> 6, lane = t & 63, g = lane >> 4, r = lane & 15;
  const int bx = blockIdx.x;
  const int b = bx / 288;
  const int rem = bx - b * 288;
  int a = 0;
  while (4 * (a + 1) * (a + 2) <= rem) ++a;
  const int rem2 = rem - 4 * a * (a + 1);
  const int m_ = rem2 / (a + 1);
  const int c = rem2 - m_ * (a + 1);
  const int st = 8 * a + m_;

  const int s0 = c * 32;                       // chunk base (16-key steps)
  const int smax = min(32, 4 * st + 4 - s0);   // staged steps (multiple of 4)
  const int nm = smax >> 2;                    // 64-key macro tiles
  const int qt = 4 * st + wv;                  // wave's global 16-row q-tile
  const int mysteps = min(qt + 1 - s0, smax);
  const int dloc = qt - s0;                    // diagonal step (mask there only)

  const size_t qoff = ((size_t)(b * 4096 + st * 64 + wv * 16 + r)) * 64 + g * 8;
  const short8v qf0 = *(const short8v*)(Qb + qoff);
  const short8v qf1 = *(const short8v*)(Qb + qoff + 32);

  float4v acc[4];
#pragma unroll
  for (int dt = 0; dt < 4; ++dt) acc[dt] = {0.f, 0.f, 0.f, 0.f};
  float mrun = -3.0e38f, lsum = 0.f;

  // staging: thread t stages 32B K (row kr) + 32B V (d-row kr), 16 keys
  const int kr = t >> 2, sq = t & 3;
  const ushort* ksrc = Kb + ((size_t)(b * 4096 + c * 512 + kr)) * 64 + sq * 16;
  const ushort* vsrc = Vt + ((size_t)(b * 64 + kr)) * 4096 + c * 512 + sq * 16;
  const int ksw = (kr & 7) << 4;
  const int kwo0 = (kr * 128 + sq * 32) ^ ksw;
  const int kwo1 = (kr * 128 + sq * 32 + 16) ^ ksw;
  const int vwb = sq * 2048 + kr * 32;
  const int sx = ((kr >> 2) & 3) ^ sq;

  uint4v kA0, kA1, vA0, vA1, kB0, kB1, vB0, vB1;
  auto stload = [&](int m, uint4v& k0, uint4v& k1, uint4v& v0, uint4v& v1) {
    const ushort* kp = ksrc + (size_t)m * 64 * 64;
    k0 = *(const uint4v*)kp;
    k1 = *(const uint4v*)(kp + 8);
    const ushort* vp = vsrc + m * 64;
    v0 = *(const uint4v*)vp;
    v1 = *(const uint4v*)(vp + 8);
  };
  auto stwrite = [&](int bi, uint4v k0, uint4v k1, uint4v v0, uint4v v1) {
    *(uint4v*)(lk + bi * 8192 + kwo0) = k0;
    *(uint4v*)(lk + bi * 8192 + kwo1) = k1;
    char* vb = lv + bi * 8192 + vwb;
    *(ull*)(vb + ((0 ^ sx) & 3) * 8) = (ull)v0[0] | ((ull)v0[1] << 32);
    *(ull*)(vb + ((1 ^ sx) & 3) * 8) = (ull)v0[2] | ((ull)v0[3] << 32);
    *(ull*)(vb + ((2 ^ sx) & 3) * 8) = (ull)v1[0] | ((ull)v1[1] << 32);
    *(ull*)(vb + ((3 ^ sx) & 3) * 8) = (ull)v1[2] | ((ull)v1[3] << 32);
  };

  auto micro = [&](int bi, int ks, bool masked) {
    const char* lkb = lk + bi * 8192;
    const char* lvb = lv + bi * 8192 + ks * 2048;
    const int krow = ks * 16 + r;
    const int rsw = (r & 7) << 4;
    const short8v k0 = *(const short8v*)(lkb + ((krow * 128 + g * 16) ^ rsw));
    const short8v k1 = *(const short8v*)(lkb + ((krow * 128 + g * 16 + 64) ^ rsw));
    float4v s = {0.f, 0.f, 0.f, 0.f};
    s = __builtin_amdgcn_mfma_f32_16x16x32_bf16(k0, qf0, s, 0, 0, 0);
    s = __builtin_amdgcn_mfma_f32_16x16x32_bf16(k1, qf1, s, 0, 0, 0);
    float u0 = s[0], u1 = s[1], u2 = s[2], u3 = s[3];
    if (masked) {  // diagonal tile: key_local=4g+i valid iff <= r
      int k4 = g << 2;
      u0 = (k4 + 0 <= r) ? u0 : -3.0e38f;
      u1 = (k4 + 1 <= r) ? u1 : -3.0e38f;
      u2 = (k4 + 2 <= r) ? u2 : -3.0e38f;
      u3 = (k4 + 3 <= r) ? u3 : -3.0e38f;
    }
    float tmax = fmaxf(fmaxf(u0, u1), fmaxf(u2, u3));
    tmax = fmaxf(tmax, __shfl_xor(tmax, 16));
    tmax = fmaxf(tmax, __shfl_xor(tmax, 32));
    float p0, p1, p2, p3;
    if (__all(tmax <= mrun)) {  // defer-max: skip rescale
      p0 = EXP2F(u0 - mrun); p1 = EXP2F(u1 - mrun);
      p2 = EXP2F(u2 - mrun); p3 = EXP2F(u3 - mrun);
      lsum += (p0 + p1) + (p2 + p3);
    } else {
      float mn = fmaxf(mrun, tmax);
      float rs = EXP2F(mrun - mn);
      mrun = mn;
      p0 = EXP2F(u0 - mn); p1 = EXP2F(u1 - mn);
      p2 = EXP2F(u2 - mn); p3 = EXP2F(u3 - mn);
      lsum = lsum * rs + ((p0 + p1) + (p2 + p3));
#pragma unroll
      for (int dt = 0; dt < 4; ++dt) acc[dt] *= rs;
    }
    short4v pf;
    pf[0] = (short)f2b(p0); pf[1] = (short)f2b(p1);
    pf[2] = (short)f2b(p2); pf[3] = (short)f2b(p3);
    const int vsl = ((g ^ (r >> 2) ^ ks) & 3) << 3;
#pragma unroll
    for (int dt = 0; dt < 4; ++dt) {
      const short4v vf = *(const short4v*)(lvb + (16 * dt + r) * 32 + vsl);
      acc[dt] = __builtin_amdgcn_mfma_f32_16x16x16bf16_1k(vf, pf, acc[dt], 0, 0, 0);
    }
  };

  // prologue: stage tile 0, preload tile 1 into regs
  stload(0, kA0, kA1, vA0, vA1);
  stwrite(0, kA0, kA1, vA0, vA1);
  if (nm > 1) stload(1, kA0, kA1, vA0, vA1);
  __syncthreads();

  for (int m = 0; m < nm; ++m) {
    if (m + 2 < nm) stload(m + 2, kB0, kB1, vB0, vB1);  // issue early
    const int nl = mysteps - m * 4;
    const int bi = m & 1;
    if (nl > 0) micro(bi, 0, m * 4 + 0 == dloc);
    if (nl > 1) micro(bi, 1, m * 4 + 1 == dloc);
    if (nl > 2) micro(bi, 2, m * 4 + 2 == dloc);
    if (nl > 3) micro(bi, 3, m * 4 + 3 == dloc);
    if (m + 1 < nm) stwrite((m + 1) & 1, kA0, kA1, vA0, vA1);
    __syncthreads();
    kA0 = kB0; kA1 = kB1; vA0 = vB0; vA1 = vB1;
  }

  lsum += __shfl_xor(lsum, 16);
  lsum += __shfl_xor(lsum, 32);

  const int slot = bx;
  const int prow = wv * 16 + r;
  if (g == 0) {
    pml[slot * 128 + prow * 2 + 0] = mrun;
    pml[slot * 128 + prow * 2 + 1] = lsum;
  }
  ushort* pp = pacc + (size_t)slot * 4096 + prow * 64;  // f16 [64 rows][64 d]
#pragma unroll
  for (int dt = 0; dt < 4; ++dt) {
    ull pk = (ull)f2h(acc[dt][0]) | ((ull)f2h(acc[dt][1]) << 16) |
             ((ull)f2h(acc[dt][2]) << 32) | ((ull)f2h(acc[dt][3]) << 48);
    *(ull*)(pp + dt * 16 + g * 4) = pk;
  }
}

// ---- P3: combine split-K partials (f16 partials, two-pass) ----
__global__ __launch_bounds__(64) void combine_kernel(
    const ushort* __restrict__ pacc, const float* __restrict__ pml,
    float* __restrict__ out) {
  const int bx = blockIdx.x;          // ((b*64 + st)*8 + rq)
  const int rq = bx & 7, st = (bx >> 3) & 63, b = bx >> 9;
  const int a = st >> 3, nc = a + 1;
  const int sb = b * 288 + 4 * a * (a + 1) + (st & 7) * (a + 1);
  const int t = threadIdx.x;
  const int row = rq * 8 + (t >> 3);
  const int d0 = (t & 7) * 8;

  float M = -3.0e38f;
  for (int p = 0; p < nc; ++p)
    M = fmaxf(M, pml[(sb + p) * 128 + row * 2]);
  float denom = 0.f;
  float4v v0 = {0.f, 0.f, 0.f, 0.f}, v1 = {0.f, 0.f, 0.f, 0.f};
  for (int p = 0; p < nc; ++p) {
    float m = pml[(sb + p) * 128 + row * 2];
    float l = pml[(sb + p) * 128 + row * 2 + 1];
    float wgt = EXP2F(m - M);
    denom += l * wgt;
    uint4v hv = *(const uint4v*)(pacc + (size_t)(sb + p) * 4096 + row * 64 + d0);
    v0[0] += wgt * h2f(hv[0] & 0xffff); v0[1] += wgt * h2f(hv[0] >> 16);
    v0[2] += wgt * h2f(hv[1] & 0xffff); v0[3] += wgt * h2f(hv[1] >> 16);
    v1[0] += wgt * h2f(hv[2] & 0xffff); v1[1] += wgt * h2f(hv[2] >> 16);
    v1[2] += wgt * h2f(hv[3] & 0xffff); v1[3] += wgt * h2f(hv[3] >> 16);
  }
  float inv = 1.0f / denom;
  float* op = out + ((size_t)(b * 4096 + st * 64 + row)) * 64 + d0;
  *(float4v*)op = v0 * inv;
  *(float4v*)(op + 4) = v1 * inv;
}

extern "C" void kernel_launch(void* const* d_in, const int* in_sizes, int n_in,
                              void* d_out, int out_size, void* d_ws, size_t ws_size,
                              hipStream_t stream) {
  const float* X  = (const float*)d_in[0];
  const float* Wq = (const float*)d_in[1];
  const float* bq = (const float*)d_in[2];
  const float* Wk = (const float*)d_in[3];
  const float* bk = (const float*)d_in[4];
  const float* Wv = (const float*)d_in[5];
  const float* bv = (const float*)d_in[6];
  float* out = (float*)d_out;

  ushort* Qb = (ushort*)d_ws;                  // [B*S][64] bf16 (scaled, exp2 dom)
  ushort* Kb = Qb + 4 * 4096 * 64;             // [B*S][64] bf16
  ushort* Vt = Kb + 4 * 4096 * 64;             // [B][64][S] bf16 (V transposed)
  ushort* Wt = Vt + 4 * 4096 * 64;             // [192][768] bf16
  float* bb  = (float*)(Wt + 192 * 768);       // [192] f32 (pad to 256)
  float* pml  = bb + 256;                      // [1152][64][2] f32
  ushort* pacc = (ushort*)(pml + 1152 * 128);  // [1152][64][64] f16 (~9.4MB)

  wpack_kernel<<<36, 256, 0, stream>>>(Wq, bq, Wk, bk, Wv, bv, Wt, bb);
  proj_kernel<<<512, 256, 0, stream>>>(X, Wt, bb, Qb, Kb, Vt);
  attn_kernel<<<1152, 256, 0, stream>>>(Qb, Kb, Vt, pacc, pml);
  combine_kernel<<<2048, 64, 0, stream>>>(pacc, pml, out);
}

// Round 6
// 174.923 us; speedup vs baseline: 1.0468x; 1.0468x over previous
//
#include <hip/hip_runtime.h>
#include <stdint.h>

// SingleHeadAttention: X(4,4096,768) f32; Wq/Wk/Wv(768,64); bq/bk/bv(64)
// out(4,4096,64) f32.
// wpack -> proj (barrier-free MFMA) -> attn (8-wave blocks, heavy-first
// split-K, role-split staging, R4-proven softmax) -> combine (f16 partials).

#define QSCALE 0.18033688011112042f  // log2(e)/sqrt(64): fold scale+base2 into Q

using short4v = __attribute__((ext_vector_type(4))) short;
using short8v = __attribute__((ext_vector_type(8))) short;
using float4v = __attribute__((ext_vector_type(4))) float;
using uint4v  = __attribute__((ext_vector_type(4))) unsigned int;
typedef unsigned long long ull;
typedef unsigned short ushort;

#if __has_builtin(__builtin_amdgcn_exp2f)
#define EXP2F(x) __builtin_amdgcn_exp2f(x)
#else
#define EXP2F(x) exp2f(x)
#endif

__device__ __forceinline__ ushort f2b(float f) {
  union { float f; unsigned u; } cv; cv.f = f;
  unsigned u = cv.u;
  u += 0x7FFFu + ((u >> 16) & 1u);   // RNE
  return (ushort)(u >> 16);
}
__device__ __forceinline__ ushort f2h(float f) {
  union { ushort u; _Float16 h; } cv; cv.h = (_Float16)f;
  return cv.u;
}
__device__ __forceinline__ float h2f(unsigned u16) {
  union { ushort u; _Float16 h; } cv; cv.u = (ushort)u16;
  return (float)cv.h;
}

// ---- P0: pack W transposed [n=192][e=768] bf16 via LDS bounce; biases f32 ----
__global__ void wpack_kernel(const float* __restrict__ Wq, const float* __restrict__ bq,
                             const float* __restrict__ Wk, const float* __restrict__ bk,
                             const float* __restrict__ Wv, const float* __restrict__ bv,
                             ushort* __restrict__ Wt, float* __restrict__ bb) {
  __shared__ float tile[64 * 65];
  const int t = threadIdx.x;
  const int m = blockIdx.x % 3, e0 = (blockIdx.x / 3) * 64;
  const float* Wsrc = (m == 0) ? Wq : (m == 1) ? Wk : Wv;
  const float sc = (m == 0) ? QSCALE : 1.0f;
#pragma unroll
  for (int i = 0; i < 16; ++i) {
    int idx = i * 256 + t, n = idx & 63, el = idx >> 6;
    tile[el * 65 + n] = Wsrc[(size_t)(e0 + el) * 64 + n];
  }
  __syncthreads();
#pragma unroll
  for (int i = 0; i < 16; ++i) {
    int idx = i * 256 + t, el = idx & 63, n = idx >> 6;
    Wt[(size_t)(m * 64 + n) * 768 + e0 + el] = f2b(tile[el * 65 + n] * sc);
  }
  if (blockIdx.x == 0 && t < 192) {
    float bvv;
    if (t < 64)       bvv = bq[t] * QSCALE;
    else if (t < 128) bvv = bk[t - 64];
    else              bvv = bv[t - 128];
    bb[t] = bvv;
  }
}

// ---- P1: QKV projection. 512 blocks x 32 rows, barrier-free direct loads. ----
__global__ __launch_bounds__(256, 4) void proj_kernel(
    const float* __restrict__ X, const ushort* __restrict__ Wt,
    const float* __restrict__ bb,
    ushort* __restrict__ Qb, ushort* __restrict__ Kb, ushort* __restrict__ Vt) {
  const int t = threadIdx.x;
  const int wv = t >> 6, lane = t & 63, g = lane >> 4, r = lane & 15;
  const int row0 = blockIdx.x * 32;

  float4v acc[3][2];
#pragma unroll
  for (int ct = 0; ct < 3; ++ct) {
    float bias = bb[wv * 48 + ct * 16 + r];
#pragma unroll
    for (int rt = 0; rt < 2; ++rt) acc[ct][rt] = {bias, bias, bias, bias};
  }

  const float* xb = X + (size_t)(row0 + r) * 768 + g * 8;
  const ushort* wb = Wt + (size_t)(wv * 48 + r) * 768 + g * 8;

#pragma unroll 2
  for (int kc = 0; kc < 12; ++kc) {
    const int k0 = kc * 64;
    short8v af[2][2];
#pragma unroll
    for (int rt = 0; rt < 2; ++rt)
#pragma unroll
      for (int ks = 0; ks < 2; ++ks) {
        const float* xp = xb + rt * 16 * 768 + k0 + ks * 32;
        float4v x0 = *(const float4v*)xp;
        float4v x1 = *(const float4v*)(xp + 4);
        short8v v;
        v[0] = (short)f2b(x0[0]); v[1] = (short)f2b(x0[1]);
        v[2] = (short)f2b(x0[2]); v[3] = (short)f2b(x0[3]);
        v[4] = (short)f2b(x1[0]); v[5] = (short)f2b(x1[1]);
        v[6] = (short)f2b(x1[2]); v[7] = (short)f2b(x1[3]);
        af[rt][ks] = v;
      }
#pragma unroll
    for (int ct = 0; ct < 3; ++ct) {
      short8v b0 = *(const short8v*)(wb + ct * 16 * 768 + k0);
      short8v b1 = *(const short8v*)(wb + ct * 16 * 768 + k0 + 32);
#pragma unroll
      for (int rt = 0; rt < 2; ++rt) {
        acc[ct][rt] = __builtin_amdgcn_mfma_f32_16x16x32_bf16(af[rt][0], b0, acc[ct][rt], 0, 0, 0);
        acc[ct][rt] = __builtin_amdgcn_mfma_f32_16x16x32_bf16(af[rt][1], b1, acc[ct][rt], 0, 0, 0);
      }
    }
  }
#pragma unroll
  for (int ct = 0; ct < 3; ++ct) {
    int n = wv * 48 + ct * 16 + r;
    int mtx = n >> 6, dl = n & 63;
#pragma unroll
    for (int rt = 0; rt < 2; ++rt) {
#pragma unroll
      for (int i = 0; i < 4; ++i) {
        int rg = row0 + rt * 16 + g * 4 + i;
        ushort hv = f2b(acc[ct][rt][i]);
        if (mtx == 0)      Qb[rg * 64 + dl] = hv;
        else if (mtx == 1) Kb[rg * 64 + dl] = hv;
        else               Vt[(size_t)(((rg >> 12) << 6) + dl) * 4096 + (rg & 4095)] = hv;
      }
    }
  }
}

// ---- P2: flash attn. 8-wave blocks (128 q-rows), heavy chunks first,
//          role-split staging (waves 0-3: V, 4-7: K), split-K 512-key chunks. ----
__global__ __launch_bounds__(512) void attn_kernel(
    const ushort* __restrict__ Qb, const ushort* __restrict__ Kb,
    const ushort* __restrict__ Vt, ushort* __restrict__ pacc,
    float* __restrict__ pml) {
  __shared__ char lds[32768];
  char* lk = lds;            // [2][64 key][128B], ^((key&7)<<4)
  char* lv = lds + 16384;    // [2][4 ks][64 d][4 slots*8B], slot^((d>>2)&3)^ks
  const int t = threadIdx.x;
  const int wv = t >> 6, lane = t & 63, g = lane >> 4, r = lane & 15;
  const int bx = blockIdx.x;
  const int b = bx / 144;
  const int j = 143 - (bx - b * 144);        // heavy chunks dispatch FIRST
  int a = 0;
  while (2 * (a + 1) * (a + 2) <= j) ++a;
  const int rm = j - 2 * a * (a + 1);
  const int m_ = rm / (a + 1);
  const int c = rm - m_ * (a + 1);
  const int st = 4 * a + m_;                 // q-supertile (128 rows)

  const int s0 = c * 32;                     // chunk base (16-key steps)
  const int smax = min(32, 8 * st + 8 - s0); // staged steps (multiple of 4)
  const int nm = smax >> 2;                  // 64-key macro tiles
  const int qt = 8 * st + wv;                // wave's global 16-row q-tile
  const int mysteps = min(qt + 1 - s0, smax);
  const int dloc = qt - s0;                  // diagonal step (mask there only)

  const size_t qoff = ((size_t)(b * 4096 + st * 128 + wv * 16 + r)) * 64 + g * 8;
  const short8v qf0 = *(const short8v*)(Qb + qoff);
  const short8v qf1 = *(const short8v*)(Qb + qoff + 32);

  float4v acc[4];
#pragma unroll
  for (int dt = 0; dt < 4; ++dt) acc[dt] = {0.f, 0.f, 0.f, 0.f};
  float mrun = -3.0e38f, lsum = 0.f;

  // role-split staging: waves 0-3 stage V, waves 4-7 stage K. 32B per thread.
  const int u = t & 255, kr = u >> 2, sq = u & 3;
  const bool isK = t >= 256;
  const ushort* src;
  int wo0, wo1, sx = 0;
  if (isK) {
    src = Kb + ((size_t)(b * 4096 + c * 512 + kr)) * 64 + sq * 16;
    wo0 = (kr * 128 + sq * 32) ^ ((kr & 7) << 4);
    wo1 = wo0 ^ 16;
  } else {
    src = Vt + ((size_t)(b * 64 + kr)) * 4096 + c * 512 + sq * 16;
    wo0 = sq * 2048 + kr * 32;   // region sq (key-slice), d-row kr
    wo1 = 0;
    sx = ((kr >> 2) & 3) ^ sq;
  }

  uint4v rA0, rA1, rB0, rB1;
  auto stload = [&](int m, uint4v& v0, uint4v& v1) {
    const ushort* p = src + (isK ? (size_t)m * 4096 : (size_t)m * 64);
    v0 = *(const uint4v*)p;
    v1 = *(const uint4v*)(p + 8);
  };
  auto stwrite = [&](int bi, uint4v v0, uint4v v1) {
    if (isK) {
      *(uint4v*)(lk + bi * 8192 + wo0) = v0;
      *(uint4v*)(lk + bi * 8192 + wo1) = v1;
    } else {
      char* vb = lv + bi * 8192 + wo0;
      *(ull*)(vb + ((0 ^ sx) & 3) * 8) = (ull)v0[0] | ((ull)v0[1] << 32);
      *(ull*)(vb + ((1 ^ sx) & 3) * 8) = (ull)v0[2] | ((ull)v0[3] << 32);
      *(ull*)(vb + ((2 ^ sx) & 3) * 8) = (ull)v1[0] | ((ull)v1[1] << 32);
      *(ull*)(vb + ((3 ^ sx) & 3) * 8) = (ull)v1[2] | ((ull)v1[3] << 32);
    }
  };

  auto micro = [&](int bi, int ks, bool masked) {
    const char* lkb = lk + bi * 8192;
    const char* lvb = lv + bi * 8192 + ks * 2048;
    const int krow = ks * 16 + r;
    const int rsw = (r & 7) << 4;
    const short8v k0 = *(const short8v*)(lkb + ((krow * 128 + g * 16) ^ rsw));
    const short8v k1 = *(const short8v*)(lkb + ((krow * 128 + g * 16 + 64) ^ rsw));
    float4v s = {0.f, 0.f, 0.f, 0.f};
    __builtin_amdgcn_s_setprio(1);
    s = __builtin_amdgcn_mfma_f32_16x16x32_bf16(k0, qf0, s, 0, 0, 0);
    s = __builtin_amdgcn_mfma_f32_16x16x32_bf16(k1, qf1, s, 0, 0, 0);
    __builtin_amdgcn_s_setprio(0);
    float u0 = s[0], u1 = s[1], u2 = s[2], u3 = s[3];
    if (masked) {  // diagonal tile: key_local=4g+i valid iff <= r
      int k4 = g << 2;
      u0 = (k4 + 0 <= r) ? u0 : -3.0e38f;
      u1 = (k4 + 1 <= r) ? u1 : -3.0e38f;
      u2 = (k4 + 2 <= r) ? u2 : -3.0e38f;
      u3 = (k4 + 3 <= r) ? u3 : -3.0e38f;
    }
    // R4-proven softmax: full row-max reduce every micro
    float tmax = fmaxf(fmaxf(u0, u1), fmaxf(u2, u3));
    tmax = fmaxf(tmax, __shfl_xor(tmax, 16));
    tmax = fmaxf(tmax, __shfl_xor(tmax, 32));
    float p0, p1, p2, p3;
    if (__all(tmax <= mrun)) {  // defer-max: skip rescale
      p0 = EXP2F(u0 - mrun); p1 = EXP2F(u1 - mrun);
      p2 = EXP2F(u2 - mrun); p3 = EXP2F(u3 - mrun);
      lsum += (p0 + p1) + (p2 + p3);
    } else {
      float mn = fmaxf(mrun, tmax);
      float rs = EXP2F(mrun - mn);
      mrun = mn;
      p0 = EXP2F(u0 - mn); p1 = EXP2F(u1 - mn);
      p2 = EXP2F(u2 - mn); p3 = EXP2F(u3 - mn);
      lsum = lsum * rs + ((p0 + p1) + (p2 + p3));
#pragma unroll
      for (int dt = 0; dt < 4; ++dt) acc[dt] *= rs;
    }
    short4v pf;
    pf[0] = (short)f2b(p0); pf[1] = (short)f2b(p1);
    pf[2] = (short)f2b(p2); pf[3] = (short)f2b(p3);
    const int vsl = ((g ^ (r >> 2) ^ ks) & 3) << 3;
    __builtin_amdgcn_s_setprio(1);
#pragma unroll
    for (int dt = 0; dt < 4; ++dt) {
      const short4v vf = *(const short4v*)(lvb + (16 * dt + r) * 32 + vsl);
      acc[dt] = __builtin_amdgcn_mfma_f32_16x16x16bf16_1k(vf, pf, acc[dt], 0, 0, 0);
    }
    __builtin_amdgcn_s_setprio(0);
  };

  // prologue: stage tile 0, preload tile 1 into regs
  stload(0, rA0, rA1);
  stwrite(0, rA0, rA1);
  if (nm > 1) stload(1, rA0, rA1);
  rB0 = rA0; rB1 = rA1;   // defined values even on short chunks
  __syncthreads();

  for (int m = 0; m < nm; ++m) {
    if (m + 2 < nm) stload(m + 2, rB0, rB1);  // issue early: hide under compute
    const int nl = mysteps - m * 4;
    const int bi = m & 1;
    if (nl > 0) micro(bi, 0, m * 4 + 0 == dloc);
    if (nl > 1) micro(bi, 1, m * 4 + 1 == dloc);
    if (nl > 2) micro(bi, 2, m * 4 + 2 == dloc);
    if (nl > 3) micro(bi, 3, m * 4 + 3 == dloc);
    if (m + 1 < nm) stwrite((m + 1) & 1, rA0, rA1);
    __syncthreads();
    rA0 = rB0; rA1 = rB1;
  }

  lsum += __shfl_xor(lsum, 16);
  lsum += __shfl_xor(lsum, 32);

  const int slot = bx;
  const int prow = wv * 16 + r;
  if (g == 0) {
    pml[slot * 256 + prow * 2 + 0] = mrun;
    pml[slot * 256 + prow * 2 + 1] = lsum;
  }
  ushort* pp = pacc + (size_t)slot * 8192 + prow * 64;  // f16 [128 rows][64 d]
#pragma unroll
  for (int dt = 0; dt < 4; ++dt) {
    ull pk = (ull)f2h(acc[dt][0]) | ((ull)f2h(acc[dt][1]) << 16) |
             ((ull)f2h(acc[dt][2]) << 32) | ((ull)f2h(acc[dt][3]) << 48);
    *(ull*)(pp + dt * 16 + g * 4) = pk;
  }
}

// ---- P3: combine split-K partials (f16 partials, two-pass) ----
__global__ __launch_bounds__(64) void combine_kernel(
    const ushort* __restrict__ pacc, const float* __restrict__ pml,
    float* __restrict__ out) {
  const int bx = blockIdx.x;          // ((b*32 + st)*32 + rq)
  const int rq = bx & 31, st = (bx >> 5) & 31, b = bx >> 10;
  const int a = st >> 2, nc = a + 1;
  const int base = 2 * a * (a + 1) + (st & 3) * (a + 1);
  const int t = threadIdx.x;
  const int row = rq * 4 + (t >> 4);
  const int d0 = (t & 15) * 4;

  float M = -3.0e38f;
  for (int p = 0; p < nc; ++p) {
    int slot = b * 144 + 143 - (base + p);
    M = fmaxf(M, pml[slot * 256 + row * 2]);
  }
  float denom = 0.f;
  float4v v0 = {0.f, 0.f, 0.f, 0.f};
  for (int p = 0; p < nc; ++p) {
    int slot = b * 144 + 143 - (base + p);
    float m = pml[slot * 256 + row * 2];
    float l = pml[slot * 256 + row * 2 + 1];
    float wgt = EXP2F(m - M);
    denom += l * wgt;
    const ushort* ap = pacc + (size_t)slot * 8192 + row * 64 + d0;
    unsigned h0 = *(const unsigned*)ap;
    unsigned h1 = *(const unsigned*)(ap + 2);
    v0[0] += wgt * h2f(h0 & 0xffff); v0[1] += wgt * h2f(h0 >> 16);
    v0[2] += wgt * h2f(h1 & 0xffff); v0[3] += wgt * h2f(h1 >> 16);
  }
  float inv = 1.0f / denom;
  *(float4v*)(out + ((size_t)(b * 4096 + st * 128 + row)) * 64 + d0) = v0 * inv;
}

extern "C" void kernel_launch(void* const* d_in, const int* in_sizes, int n_in,
                              void* d_out, int out_size, void* d_ws, size_t ws_size,
                              hipStream_t stream) {
  const float* X  = (const float*)d_in[0];
  const float* Wq = (const float*)d_in[1];
  const float* bq = (const float*)d_in[2];
  const float* Wk = (const float*)d_in[3];
  const float* bk = (const float*)d_in[4];
  const float* Wv = (const float*)d_in[5];
  const float* bv = (const float*)d_in[6];
  float* out = (float*)d_out;

  ushort* Qb = (ushort*)d_ws;                  // [B*S][64] bf16 (scaled, exp2 dom)
  ushort* Kb = Qb + 4 * 4096 * 64;             // [B*S][64] bf16
  ushort* Vt = Kb + 4 * 4096 * 64;             // [B][64][S] bf16 (V transposed)
  ushort* Wt = Vt + 4 * 4096 * 64;             // [192][768] bf16
  float* bb  = (float*)(Wt + 192 * 768);       // [192] f32 (pad to 256)
  float* pml  = bb + 256;                      // [576][128][2] f32
  ushort* pacc = (ushort*)(pml + 576 * 256);   // [576][128][64] f16 (~9.4MB)

  wpack_kernel<<<36, 256, 0, stream>>>(Wq, bq, Wk, bk, Wv, bv, Wt, bb);
  proj_kernel<<<512, 256, 0, stream>>>(X, Wt, bb, Qb, Kb, Vt);
  attn_kernel<<<576, 512, 0, stream>>>(Qb, Kb, Vt, pacc, pml);
  combine_kernel<<<4096, 64, 0, stream>>>(pacc, pml, out);
}

// Round 9
// 156.997 us; speedup vs baseline: 1.1663x; 1.1142x over previous
//
#include <hip/hip_runtime.h>
#include <stdint.h>

// SingleHeadAttention: X(4,4096,768) f32; Wq/Wk/Wv(768,64); bq/bk/bv(64)
// out(4,4096,64) f32.
// wpack (frag-layout W) -> proj (LDS-staged coalesced MFMA) ->
// attn (8-wave blocks, heavy-first split-K, role-split staging) -> combine.

#define QSCALE 0.18033688011112042f  // log2(e)/sqrt(64): fold scale+base2 into Q

using short4v = __attribute__((ext_vector_type(4))) short;
using short8v = __attribute__((ext_vector_type(8))) short;
using float4v = __attribute__((ext_vector_type(4))) float;
using uint4v  = __attribute__((ext_vector_type(4))) unsigned int;
typedef unsigned long long ull;
typedef unsigned short ushort;

#if __has_builtin(__builtin_amdgcn_exp2f)
#define EXP2F(x) __builtin_amdgcn_exp2f(x)
#else
#define EXP2F(x) exp2f(x)
#endif

__device__ __forceinline__ ushort f2b(float f) {
  union { float f; unsigned u; } cv; cv.f = f;
  unsigned u = cv.u;
  u += 0x7FFFu + ((u >> 16) & 1u);   // RNE
  return (ushort)(u >> 16);
}
__device__ __forceinline__ ushort f2h(float f) {
  union { ushort u; _Float16 h; } cv; cv.h = (_Float16)f;
  return cv.u;
}
__device__ __forceinline__ float h2f(unsigned u16) {
  union { ushort u; _Float16 h; } cv; cv.u = (ushort)u16;
  return (float)cv.h;
}
// pack two raw-f32-bit values to bf16x2 (int-only RNE)
__device__ __forceinline__ unsigned bpk(unsigned a, unsigned b) {
  a += 0x7FFFu + ((a >> 16) & 1u);
  b += 0x7FFFu + ((b >> 16) & 1u);
  return (a >> 16) | (b & 0xFFFF0000u);
}

// ---- P0: pack W into MFMA fragment layout + biases.
// Wf element for frag(kc,ks,nt), lane(g*16+r), elem j  <->  W[n=nt*16+r][k=kc*64+ks*32+g*8+j]
__global__ void wpack_kernel(const float* __restrict__ Wq, const float* __restrict__ bq,
                             const float* __restrict__ Wk, const float* __restrict__ bk,
                             const float* __restrict__ Wv, const float* __restrict__ bv,
                             ushort* __restrict__ Wf, float* __restrict__ bb) {
  const int t = threadIdx.x;
  const int gid = blockIdx.x * 256 + t;      // 576*256 == 147456 == 3*768*64
  const int mtx = gid / 49152;
  const int rem = gid - mtx * 49152;         // k*64 + dl  (coalesced read)
  const int k = rem >> 6, dl = rem & 63;
  const float* Wsrc = (mtx == 0) ? Wq : (mtx == 1) ? Wk : Wv;
  float val = Wsrc[rem] * ((mtx == 0) ? QSCALE : 1.0f);
  const int n = mtx * 64 + dl;
  const int nt = n >> 4, r = n & 15;
  const int kc = k >> 6, k6 = k & 63;
  const int ks = k6 >> 5, g = (k6 >> 3) & 3, j = k6 & 7;
  Wf[(size_t)((kc * 2 + ks) * 12 + nt) * 512 + (g * 16 + r) * 8 + j] = f2b(val);
  if (blockIdx.x == 0 && t < 192) {
    float bvv;
    if (t < 64)       bvv = bq[t] * QSCALE;
    else if (t < 128) bvv = bk[t - 64];
    else              bvv = bv[t - 128];
    bb[t] = bvv;
  }
}

// ---- P1: QKV projection. 512 blocks x 32 rows x 8 waves; X via LDS
// (coalesced 16B/thread loads, seg-XOR swizzle), W frags contiguous 1KB/wave. ----
__global__ __launch_bounds__(512) void proj_kernel(
    const float* __restrict__ X, const ushort* __restrict__ Wf,
    const float* __restrict__ bb,
    ushort* __restrict__ Qb, ushort* __restrict__ Kb, ushort* __restrict__ Vt) {
  __shared__ char lx[2][8192];  // [32 rows][16 segs x 16B], phys seg = seg ^ (row&15)
  const int t = threadIdx.x;
  const int wv = t >> 6, lane = t & 63, g = lane >> 4, r = lane & 15;
  const int rh = wv >> 2, nq = wv & 3;   // row-half (16 rows), n-quarter (48 cols)
  const int row0 = blockIdx.x * 32;

  float4v acc[3];
#pragma unroll
  for (int ct = 0; ct < 3; ++ct) {
    float bias = bb[nq * 48 + ct * 16 + r];
    acc[ct] = {bias, bias, bias, bias};
  }

  // staging map: thread t covers (row = t>>4, global seg = t&15)
  const int srow = t >> 4, sseg = t & 15;
  const float* gsrc = X + (size_t)(row0 + srow) * 768 + sseg * 4;
  const int woff = srow * 256 + ((sseg ^ (srow & 15)) << 4);

  uint4v xr = *(const uint4v*)gsrc;   // chunk 0
  *(uint4v*)(lx[0] + woff) = xr;
  __syncthreads();

  const int rowb = (rh * 16 + r) * 256;
#pragma unroll 2
  for (int kc = 0; kc < 12; ++kc) {
    if (kc < 11) xr = *(const uint4v*)(gsrc + (kc + 1) * 64);  // issue early
    const char* lb = lx[kc & 1];
#pragma unroll
    for (int ks = 0; ks < 2; ++ks) {
      const int c0 = 2 * g + 8 * ks;
      uint4v lo = *(const uint4v*)(lb + rowb + (((c0) ^ r) << 4));
      uint4v hi = *(const uint4v*)(lb + rowb + (((c0 + 1) ^ r) << 4));
      union { unsigned u[4]; short8v s; } a;
      a.u[0] = bpk(lo[0], lo[1]); a.u[1] = bpk(lo[2], lo[3]);
      a.u[2] = bpk(hi[0], hi[1]); a.u[3] = bpk(hi[2], hi[3]);
      const ushort* wp = Wf + (size_t)((kc * 2 + ks) * 12 + nq * 3) * 512 + lane * 8;
#pragma unroll
      for (int ct = 0; ct < 3; ++ct) {
        short8v bfr = *(const short8v*)(wp + ct * 512);
        acc[ct] = __builtin_amdgcn_mfma_f32_16x16x32_bf16(a.s, bfr, acc[ct], 0, 0, 0);
      }
    }
    __syncthreads();               // all waves done reading buf (kc+1)&1
    if (kc < 11) *(uint4v*)(lx[(kc + 1) & 1] + woff) = xr;
    __syncthreads();               // buf kc+1 ready
  }

#pragma unroll
  for (int ct = 0; ct < 3; ++ct) {
    int n = nq * 48 + ct * 16 + r;
    int mtx = n >> 6, dl = n & 63;
#pragma unroll
    for (int i = 0; i < 4; ++i) {
      int rg = row0 + rh * 16 + g * 4 + i;
      ushort hv = f2b(acc[ct][i]);
      if (mtx == 0)      Qb[rg * 64 + dl] = hv;
      else if (mtx == 1) Kb[rg * 64 + dl] = hv;
      else               Vt[(size_t)(((rg >> 12) << 6) + dl) * 4096 + (rg & 4095)] = hv;
    }
  }
}

// ---- P2: flash attn. 8-wave blocks (128 q-rows), heavy chunks first,
//          role-split staging (waves 0-3: V, 4-7: K), split-K 512-key chunks. ----
__global__ __launch_bounds__(512) void attn_kernel(
    const ushort* __restrict__ Qb, const ushort* __restrict__ Kb,
    const ushort* __restrict__ Vt, ushort* __restrict__ pacc,
    float* __restrict__ pml) {
  __shared__ char lds[32768];
  char* lk = lds;            // [2][64 key][128B], ^((key&7)<<4)
  char* lv = lds + 16384;    // [2][4 ks][64 d][4 slots*8B], slot^((d>>2)&3)^ks
  const int t = threadIdx.x;
  const int wv = t >> 6, lane = t & 63, g = lane >> 4, r = lane & 15;
  const int bx = blockIdx.x;
  const int b = bx / 144;
  const int j = 143 - (bx - b * 144);        // heavy chunks dispatch FIRST
  int a = 0;
  while (2 * (a + 1) * (a + 2) <= j) ++a;
  const int rm = j - 2 * a * (a + 1);
  const int m_ = rm / (a + 1);
  const int c = rm - m_ * (a + 1);
  const int st = 4 * a + m_;                 // q-supertile (128 rows)

  const int s0 = c * 32;                     // chunk base (16-key steps)
  const int smax = min(32, 8 * st + 8 - s0); // staged steps (multiple of 4)
  const int nm = smax >> 2;                  // 64-key macro tiles
  const int qt = 8 * st + wv;                // wave's global 16-row q-tile
  const int mysteps = min(qt + 1 - s0, smax);
  const int dloc = qt - s0;                  // diagonal step (mask there only)

  const size_t qoff = ((size_t)(b * 4096 + st * 128 + wv * 16 + r)) * 64 + g * 8;
  const short8v qf0 = *(const short8v*)(Qb + qoff);
  const short8v qf1 = *(const short8v*)(Qb + qoff + 32);

  float4v acc[4];
#pragma unroll
  for (int dt = 0; dt < 4; ++dt) acc[dt] = {0.f, 0.f, 0.f, 0.f};
  float mrun = -3.0e38f, lsum = 0.f;

  // role-split staging: waves 0-3 stage V, waves 4-7 stage K. 32B per thread.
  const int u = t & 255, kr = u >> 2, sq = u & 3;
  const bool isK = t >= 256;
  const ushort* src;
  int wo0, wo1, sx = 0;
  if (isK) {
    src = Kb + ((size_t)(b * 4096 + c * 512 + kr)) * 64 + sq * 16;
    wo0 = (kr * 128 + sq * 32) ^ ((kr & 7) << 4);
    wo1 = wo0 ^ 16;
  } else {
    src = Vt + ((size_t)(b * 64 + kr)) * 4096 + c * 512 + sq * 16;
    wo0 = sq * 2048 + kr * 32;   // region sq (key-slice), d-row kr
    wo1 = 0;
    sx = ((kr >> 2) & 3) ^ sq;
  }

  uint4v rA0, rA1, rB0, rB1;
  auto stload = [&](int m, uint4v& v0, uint4v& v1) {
    const ushort* p = src + (isK ? (size_t)m * 4096 : (size_t)m * 64);
    v0 = *(const uint4v*)p;
    v1 = *(const uint4v*)(p + 8);
  };
  auto stwrite = [&](int bi, uint4v v0, uint4v v1) {
    if (isK) {
      *(uint4v*)(lk + bi * 8192 + wo0) = v0;
      *(uint4v*)(lk + bi * 8192 + wo1) = v1;
    } else {
      char* vb = lv + bi * 8192 + wo0;
      *(ull*)(vb + ((0 ^ sx) & 3) * 8) = (ull)v0[0] | ((ull)v0[1] << 32);
      *(ull*)(vb + ((1 ^ sx) & 3) * 8) = (ull)v0[2] | ((ull)v0[3] << 32);
      *(ull*)(vb + ((2 ^ sx) & 3) * 8) = (ull)v1[0] | ((ull)v1[1] << 32);
      *(ull*)(vb + ((3 ^ sx) & 3) * 8) = (ull)v1[2] | ((ull)v1[3] << 32);
    }
  };

  auto micro = [&](int bi, int ks, bool masked) {
    const char* lkb = lk + bi * 8192;
    const char* lvb = lv + bi * 8192 + ks * 2048;
    const int krow = ks * 16 + r;
    const int rsw = (r & 7) << 4;
    const short8v k0 = *(const short8v*)(lkb + ((krow * 128 + g * 16) ^ rsw));
    const short8v k1 = *(const short8v*)(lkb + ((krow * 128 + g * 16 + 64) ^ rsw));
    float4v s = {0.f, 0.f, 0.f, 0.f};
    __builtin_amdgcn_s_setprio(1);
    s = __builtin_amdgcn_mfma_f32_16x16x32_bf16(k0, qf0, s, 0, 0, 0);
    s = __builtin_amdgcn_mfma_f32_16x16x32_bf16(k1, qf1, s, 0, 0, 0);
    __builtin_amdgcn_s_setprio(0);
    float u0 = s[0], u1 = s[1], u2 = s[2], u3 = s[3];
    if (masked) {  // diagonal tile: key_local=4g+i valid iff <= r
      int k4 = g << 2;
      u0 = (k4 + 0 <= r) ? u0 : -3.0e38f;
      u1 = (k4 + 1 <= r) ? u1 : -3.0e38f;
      u2 = (k4 + 2 <= r) ? u2 : -3.0e38f;
      u3 = (k4 + 3 <= r) ? u3 : -3.0e38f;
    }
    float tmax = fmaxf(fmaxf(u0, u1), fmaxf(u2, u3));
    tmax = fmaxf(tmax, __shfl_xor(tmax, 16));
    tmax = fmaxf(tmax, __shfl_xor(tmax, 32));
    float p0, p1, p2, p3;
    if (__all(tmax <= mrun)) {  // defer-max: skip rescale
      p0 = EXP2F(u0 - mrun); p1 = EXP2F(u1 - mrun);
      p2 = EXP2F(u2 - mrun); p3 = EXP2F(u3 - mrun);
      lsum += (p0 + p1) + (p2 + p3);
    } else {
      float mn = fmaxf(mrun, tmax);
      float rs = EXP2F(mrun - mn);
      mrun = mn;
      p0 = EXP2F(u0 - mn); p1 = EXP2F(u1 - mn);
      p2 = EXP2F(u2 - mn); p3 = EXP2F(u3 - mn);
      lsum = lsum * rs + ((p0 + p1) + (p2 + p3));
#pragma unroll
      for (int dt = 0; dt < 4; ++dt) acc[dt] *= rs;
    }
    short4v pf;
    pf[0] = (short)f2b(p0); pf[1] = (short)f2b(p1);
    pf[2] = (short)f2b(p2); pf[3] = (short)f2b(p3);
    const int vsl = ((g ^ (r >> 2) ^ ks) & 3) << 3;
    __builtin_amdgcn_s_setprio(1);
#pragma unroll
    for (int dt = 0; dt < 4; ++dt) {
      const short4v vf = *(const short4v*)(lvb + (16 * dt + r) * 32 + vsl);
      acc[dt] = __builtin_amdgcn_mfma_f32_16x16x16bf16_1k(vf, pf, acc[dt], 0, 0, 0);
    }
    __builtin_amdgcn_s_setprio(0);
  };

  // prologue: stage tile 0, preload tile 1 into regs
  stload(0, rA0, rA1);
  stwrite(0, rA0, rA1);
  if (nm > 1) stload(1, rA0, rA1);
  rB0 = rA0; rB1 = rA1;   // defined values even on short chunks
  __syncthreads();

  for (int m = 0; m < nm; ++m) {
    if (m + 2 < nm) stload(m + 2, rB0, rB1);  // issue early: hide under compute
    const int nl = mysteps - m * 4;
    const int bi = m & 1;
    if (nl > 0) micro(bi, 0, m * 4 + 0 == dloc);
    if (nl > 1) micro(bi, 1, m * 4 + 1 == dloc);
    if (nl > 2) micro(bi, 2, m * 4 + 2 == dloc);
    if (nl > 3) micro(bi, 3, m * 4 + 3 == dloc);
    if (m + 1 < nm) stwrite((m + 1) & 1, rA0, rA1);
    __syncthreads();
    rA0 = rB0; rA1 = rB1;
  }

  lsum += __shfl_xor(lsum, 16);
  lsum += __shfl_xor(lsum, 32);

  const int slot = bx;
  const int prow = wv * 16 + r;
  if (g == 0) {
    pml[slot * 256 + prow * 2 + 0] = mrun;
    pml[slot * 256 + prow * 2 + 1] = lsum;
  }
  ushort* pp = pacc + (size_t)slot * 8192 + prow * 64;  // f16 [128 rows][64 d]
#pragma unroll
  for (int dt = 0; dt < 4; ++dt) {
    ull pk = (ull)f2h(acc[dt][0]) | ((ull)f2h(acc[dt][1]) << 16) |
             ((ull)f2h(acc[dt][2]) << 32) | ((ull)f2h(acc[dt][3]) << 48);
    *(ull*)(pp + dt * 16 + g * 4) = pk;
  }
}

// ---- P3: combine split-K partials (f16 partials, two-pass) ----
__global__ __launch_bounds__(64) void combine_kernel(
    const ushort* __restrict__ pacc, const float* __restrict__ pml,
    float* __restrict__ out) {
  const int bx = blockIdx.x;          // ((b*32 + st)*32 + rq)
  const int rq = bx & 31, st = (bx >> 5) & 31, b = bx >> 10;
  const int a = st >> 2, nc = a + 1;
  const int base = 2 * a * (a + 1) + (st & 3) * (a + 1);
  const int t = threadIdx.x;
  const int row = rq * 4 + (t >> 4);
  const int d0 = (t & 15) * 4;

  float M = -3.0e38f;
  for (int p = 0; p < nc; ++p) {
    int slot = b * 144 + 143 - (base + p);
    M = fmaxf(M, pml[slot * 256 + row * 2]);
  }
  float denom = 0.f;
  float4v v0 = {0.f, 0.f, 0.f, 0.f};
  for (int p = 0; p < nc; ++p) {
    int slot = b * 144 + 143 - (base + p);
    float m = pml[slot * 256 + row * 2];
    float l = pml[slot * 256 + row * 2 + 1];
    float wgt = EXP2F(m - M);
    denom += l * wgt;
    const ushort* ap = pacc + (size_t)slot * 8192 + row * 64 + d0;
    unsigned h0 = *(const unsigned*)ap;
    unsigned h1 = *(const unsigned*)(ap + 2);
    v0[0] += wgt * h2f(h0 & 0xffff); v0[1] += wgt * h2f(h0 >> 16);
    v0[2] += wgt * h2f(h1 & 0xffff); v0[3] += wgt * h2f(h1 >> 16);
  }
  float inv = 1.0f / denom;
  *(float4v*)(out + ((size_t)(b * 4096 + st * 128 + row)) * 64 + d0) = v0 * inv;
}

extern "C" void kernel_launch(void* const* d_in, const int* in_sizes, int n_in,
                              void* d_out, int out_size, void* d_ws, size_t ws_size,
                              hipStream_t stream) {
  const float* X  = (const float*)d_in[0];
  const float* Wq = (const float*)d_in[1];
  const float* bq = (const float*)d_in[2];
  const float* Wk = (const float*)d_in[3];
  const float* bk = (const float*)d_in[4];
  const float* Wv = (const float*)d_in[5];
  const float* bv = (const float*)d_in[6];
  float* out = (float*)d_out;

  ushort* Qb = (ushort*)d_ws;                  // [B*S][64] bf16 (scaled, exp2 dom)
  ushort* Kb = Qb + 4 * 4096 * 64;             // [B*S][64] bf16
  ushort* Vt = Kb + 4 * 4096 * 64;             // [B][64][S] bf16 (V transposed)
  ushort* Wf = Vt + 4 * 4096 * 64;             // [288 frags][512] bf16 frag layout
  float* bb  = (float*)(Wf + 192 * 768);       // [192] f32 (pad to 256)
  float* pml  = bb + 256;                      // [576][128][2] f32
  ushort* pacc = (ushort*)(pml + 576 * 256);   // [576][128][64] f16 (~9.4MB)

  wpack_kernel<<<576, 256, 0, stream>>>(Wq, bq, Wk, bk, Wv, bv, Wf, bb);
  proj_kernel<<<512, 512, 0, stream>>>(X, Wf, bb, Qb, Kb, Vt);
  attn_kernel<<<576, 512, 0, stream>>>(Qb, Kb, Vt, pacc, pml);
  combine_kernel<<<4096, 64, 0, stream>>>(pacc, pml, out);
}